// Round 5
// baseline (1257.114 us; speedup 1.0000x reference)
//
#include <hip/hip_runtime.h>
#include <hip/hip_bf16.h>

#define NNODES 12000
#define NEDGES 384000
#define NETOT  (NEDGES + NNODES)   /* 396000 incl self-loops */
#define FIN    4
#define FHID   50
#define FOUT   1433
#define KP     1440                /* FOUT padded to multiple of 32; also bytes/row in fp8 */
#define MP     12032               /* NNODES padded to multiple of 128 */
#define NEG_SLOPE 0.2f

typedef __hip_bfloat16 bf16_t;
typedef float f32x4 __attribute__((ext_vector_type(4)));
typedef float f32x2 __attribute__((ext_vector_type(2)));

__device__ __forceinline__ float  b2f(bf16_t h) { return __bfloat162float(h); }
__device__ __forceinline__ bf16_t f2b(float f)  { return __float2bfloat16(f); }

// ---------------- init: deg=1 (self loop), zero pad rows of h2 (fp8) ----------------
__global__ void k_init(int* __restrict__ deg, unsigned char* __restrict__ h2) {
    int i = blockIdx.x * blockDim.x + threadIdx.x;
    int stride = gridDim.x * blockDim.x;
    for (int v = i; v < NNODES; v += stride) deg[v] = 1;
    const size_t padN = (size_t)(MP - NNODES) * KP;   // bytes
    for (size_t t = i; t < padN; t += stride) h2[(size_t)NNODES * KP + t] = 0;
}

// ---------------- count real edges by dst ----------------
__global__ void k_count(const int* __restrict__ ei, int* __restrict__ deg) {
    int i = blockIdx.x * blockDim.x + threadIdx.x;
    if (i < NEDGES) atomicAdd(&deg[ei[NEDGES + i]], 1);
}

// ---------------- single-block exclusive scan -> rowptr[N+1] ----------------
__global__ __launch_bounds__(1024) void k_scan(const int* __restrict__ deg, int* __restrict__ rowptr) {
    __shared__ int sd[1024];
    __shared__ int carry;
    int tid = threadIdx.x;
    if (tid == 0) { carry = 0; rowptr[0] = 0; }
    __syncthreads();
    for (int base = 0; base < NNODES; base += 1024) {
        int v = (base + tid < NNODES) ? deg[base + tid] : 0;
        sd[tid] = v;
        __syncthreads();
        for (int off = 1; off < 1024; off <<= 1) {
            int t = (tid >= off) ? sd[tid - off] : 0;
            __syncthreads();
            sd[tid] += t;
            __syncthreads();
        }
        int inc = sd[tid] + carry;
        if (base + tid < NNODES) rowptr[base + tid + 1] = inc;
        __syncthreads();
        if (tid == 1023) carry = sd[1023] + carry;
        __syncthreads();
    }
}

__global__ void k_cursor(const int* __restrict__ rowptr, int* __restrict__ cursor) {
    int i = blockIdx.x * blockDim.x + threadIdx.x;
    if (i < NNODES) cursor[i] = rowptr[i];
}

// ---------------- fill CSR src lists (incl self loops) ----------------
__global__ void k_fill(const int* __restrict__ ei, int* __restrict__ cursor, int* __restrict__ csrc) {
    int i = blockIdx.x * blockDim.x + threadIdx.x;
    if (i < NETOT) {
        int s, d;
        if (i < NEDGES) { s = ei[i]; d = ei[NEDGES + i]; }
        else            { s = d = i - NEDGES; }
        int pos = atomicAdd(&cursor[d], 1);
        csrc[pos] = s;
    }
}

// ---------------- layer1 linear: h1pre = x @ W1, al1/ar1 logit parts ----------------
__global__ __launch_bounds__(256) void k_linear1(
        const bf16_t* __restrict__ x, const bf16_t* __restrict__ W1,
        const bf16_t* __restrict__ as1, const bf16_t* __restrict__ ad1,
        float* __restrict__ h1pre, float* __restrict__ al, float* __restrict__ ar) {
    __shared__ float sW[FIN * FHID];
    __shared__ float sa[FHID], sdl[FHID];
    int tid = threadIdx.x;
    if (tid < FIN * FHID) sW[tid] = b2f(W1[tid]);
    if (tid < FHID) { sa[tid] = b2f(as1[tid]); sdl[tid] = b2f(ad1[tid]); }
    __syncthreads();
    int i = blockIdx.x * 256 + tid;
    if (i >= NNODES) return;
    float x0 = b2f(x[i * 4 + 0]), x1 = b2f(x[i * 4 + 1]);
    float x2 = b2f(x[i * 4 + 2]), x3 = b2f(x[i * 4 + 3]);
    float hal = 0.f, har = 0.f;
    for (int j = 0; j < FHID; ++j) {
        float h = x0 * sW[j] + x1 * sW[FHID + j] + x2 * sW[2 * FHID + j] + x3 * sW[3 * FHID + j];
        h1pre[(size_t)i * FHID + j] = h;
        hal += h * sa[j];
        har += h * sdl[j];
    }
    al[i] = hal; ar[i] = har;
}

// ---------------- layer1 softmax-aggregate (one wave per dst) ----------------
__global__ __launch_bounds__(64) void k_agg1(
        const float* __restrict__ h1pre, const float* __restrict__ al, const float* __restrict__ ar,
        const int* __restrict__ rowptr, const int* __restrict__ csrc,
        const bf16_t* __restrict__ b1, float* __restrict__ h1) {
    int v = blockIdx.x, tid = threadIdx.x;
    int s0 = rowptr[v], s1 = rowptr[v + 1];
    float arv = ar[v];
    float m = -1e30f;
    for (int e = s0 + tid; e < s1; e += 64) {
        float l = al[csrc[e]] + arv;
        l = l > 0.f ? l : NEG_SLOPE * l;
        m = fmaxf(m, l);
    }
#pragma unroll
    for (int off = 32; off; off >>= 1) m = fmaxf(m, __shfl_xor(m, off, 64));
    __shared__ float sw[64];
    __shared__ int ssrc[64];
    float acc = 0.f, ssum = 0.f;
    for (int base = s0; base < s1; base += 64) {
        int e = base + tid;
        float w = 0.f; int si = 0;
        if (e < s1) {
            si = csrc[e];
            float l = al[si] + arv;
            l = l > 0.f ? l : NEG_SLOPE * l;
            w = __expf(l - m);
        }
        ssum += w;
        sw[tid] = w; ssrc[tid] = si;
        __syncthreads();
        int cnt = min(64, s1 - base);
        if (tid < FHID) {
#pragma unroll 4
            for (int j = 0; j < cnt; ++j)
                acc += sw[j] * h1pre[(size_t)ssrc[j] * FHID + tid];
        }
        __syncthreads();
    }
#pragma unroll
    for (int off = 32; off; off >>= 1) ssum += __shfl_xor(ssum, off, 64);
    if (tid < FHID) {
        float o = acc / ssum + b2f(b1[tid]);
        h1[(size_t)v * FHID + tid] = fmaxf(o, 0.f);
    }
}

// ---------------- layer2 linear: 4 nodes/block, h2pre (fp8 e4m3) = h1 @ W2, al2/ar2 ----------------
__global__ __launch_bounds__(256) void k_linear2(
        const float* __restrict__ h1, const bf16_t* __restrict__ W2,
        const bf16_t* __restrict__ as2, const bf16_t* __restrict__ ad2,
        unsigned char* __restrict__ h2pre, float* __restrict__ al2, float* __restrict__ ar2) {
    int v0 = blockIdx.x * 4, tid = threadIdx.x;
    __shared__ float sh[4][FHID];
    if (tid < 4 * FHID) sh[tid / FHID][tid % FHID] = h1[(size_t)v0 * FHID + tid];
    __syncthreads();
    float pal[4] = {0.f, 0.f, 0.f, 0.f}, par[4] = {0.f, 0.f, 0.f, 0.f};
#pragma unroll
    for (int i = 0; i < 3; ++i) {
        int f0 = i * 512 + 2 * tid;          // even feature index
        if (f0 < KP) {
            float d0[4] = {0.f, 0.f, 0.f, 0.f}, d1[4] = {0.f, 0.f, 0.f, 0.f};
            bool ok0 = f0 < FOUT, ok1 = f0 + 1 < FOUT;
            if (ok0) {
                int f1 = ok1 ? f0 + 1 : f0;  // safe aliased read when f0+1 OOB
#pragma unroll 10
                for (int k = 0; k < FHID; ++k) {
                    float w0 = b2f(W2[k * FOUT + f0]);
                    float w1 = b2f(W2[k * FOUT + f1]);
#pragma unroll
                    for (int c = 0; c < 4; ++c) {
                        d0[c] += sh[c][k] * w0;
                        d1[c] += sh[c][k] * w1;
                    }
                }
                if (!ok1) { d1[0] = d1[1] = d1[2] = d1[3] = 0.f; }
                float sa0 = b2f(as2[f0]), sd0 = b2f(ad2[f0]);
                float sa1 = ok1 ? b2f(as2[f0 + 1]) : 0.f;
                float sd1 = ok1 ? b2f(ad2[f0 + 1]) : 0.f;
#pragma unroll
                for (int c = 0; c < 4; ++c) {
                    pal[c] += d0[c] * sa0 + d1[c] * sa1;
                    par[c] += d0[c] * sd0 + d1[c] * sd1;
                }
            }
#pragma unroll
            for (int c = 0; c < 4; ++c) {
                int pk = __builtin_amdgcn_cvt_pk_fp8_f32(d0[c], d1[c], 0, false);
                *(unsigned short*)(h2pre + (size_t)(v0 + c) * KP + f0) = (unsigned short)pk;
            }
        }
    }
#pragma unroll
    for (int off = 32; off; off >>= 1)
#pragma unroll
        for (int c = 0; c < 4; ++c) {
            pal[c] += __shfl_xor(pal[c], off, 64);
            par[c] += __shfl_xor(par[c], off, 64);
        }
    __shared__ float rA[4][4], rB[4][4];
    int wave = tid >> 6, lane = tid & 63;
    if (lane == 0)
#pragma unroll
        for (int c = 0; c < 4; ++c) { rA[wave][c] = pal[c]; rB[wave][c] = par[c]; }
    __syncthreads();
    if (tid < 4) {
        al2[v0 + tid] = rA[0][tid] + rA[1][tid] + rA[2][tid] + rA[3][tid];
        ar2[v0 + tid] = rB[0][tid] + rB[1][tid] + rB[2][tid] + rB[3][tid];
    }
}

// ---------------- layer2 softmax-aggregate: fp8 uint2 gather (8B = 8 feats/lane) ----------------
__global__ __launch_bounds__(256) void k_agg2(
        const unsigned char* __restrict__ h2pre, const float* __restrict__ al, const float* __restrict__ ar,
        const int* __restrict__ rowptr, const int* __restrict__ csrc,
        const bf16_t* __restrict__ bias2, unsigned char* __restrict__ h2) {
    int v = blockIdx.x, tid = threadIdx.x;
    int s0 = rowptr[v], s1 = rowptr[v + 1];
    float arv = ar[v];
    float m = -1e30f;
    for (int e = s0 + tid; e < s1; e += 256) {
        float l = al[csrc[e]] + arv;
        l = l > 0.f ? l : NEG_SLOPE * l;
        m = fmaxf(m, l);
    }
#pragma unroll
    for (int off = 32; off; off >>= 1) m = fmaxf(m, __shfl_xor(m, off, 64));
    __shared__ float red[4];
    int wave = tid >> 6, lane = tid & 63;
    if (lane == 0) red[wave] = m;
    __syncthreads();
    m = fmaxf(fmaxf(red[0], red[1]), fmaxf(red[2], red[3]));
    __syncthreads();

    float acc[8] = {0.f, 0.f, 0.f, 0.f, 0.f, 0.f, 0.f, 0.f};
    float ssum = 0.f;
    __shared__ float sw[256];
    __shared__ int ssrc[256];
    const bool act = tid < (KP / 8);          // 180 lanes cover the 1440-B row
    for (int base = s0; base < s1; base += 256) {
        int e = base + tid;
        float w = 0.f; int si = 0;
        if (e < s1) {
            si = csrc[e];
            float l = al[si] + arv;
            l = l > 0.f ? l : NEG_SLOPE * l;
            w = __expf(l - m);
        }
        ssum += w;
        sw[tid] = w; ssrc[tid] = si;
        __syncthreads();
        int cnt = min(256, s1 - base);
        if (act) {
#pragma unroll 4
            for (int j = 0; j < cnt; ++j) {
                float wj = sw[j];
                const uint2* hp = (const uint2*)(h2pre + (size_t)ssrc[j] * KP);
                uint2 p = hp[tid];
                f32x2 e0 = __builtin_amdgcn_cvt_pk_f32_fp8(p.x, false);
                f32x2 e1 = __builtin_amdgcn_cvt_pk_f32_fp8(p.x, true);
                f32x2 e2 = __builtin_amdgcn_cvt_pk_f32_fp8(p.y, false);
                f32x2 e3 = __builtin_amdgcn_cvt_pk_f32_fp8(p.y, true);
                acc[0] += wj * e0.x; acc[1] += wj * e0.y;
                acc[2] += wj * e1.x; acc[3] += wj * e1.y;
                acc[4] += wj * e2.x; acc[5] += wj * e2.y;
                acc[6] += wj * e3.x; acc[7] += wj * e3.y;
            }
        }
        __syncthreads();
    }
#pragma unroll
    for (int off = 32; off; off >>= 1) ssum += __shfl_xor(ssum, off, 64);
    if (lane == 0) red[wave] = ssum;
    __syncthreads();
    float inv = 1.f / (red[0] + red[1] + red[2] + red[3]);

    if (act) {
        int fb = 8 * tid;
        float o[8];
#pragma unroll
        for (int t = 0; t < 8; ++t) {
            int f = fb + t;
            o[t] = (f < FOUT) ? fmaxf(acc[t] * inv + b2f(bias2[f]), 0.f) : 0.f;
        }
        uint2 pk;
        int w0 = __builtin_amdgcn_cvt_pk_fp8_f32(o[0], o[1], 0, false);
        pk.x = (unsigned)__builtin_amdgcn_cvt_pk_fp8_f32(o[2], o[3], w0, true);
        int w1 = __builtin_amdgcn_cvt_pk_fp8_f32(o[4], o[5], 0, false);
        pk.y = (unsigned)__builtin_amdgcn_cvt_pk_fp8_f32(o[6], o[7], w1, true);
        *(uint2*)(h2 + (size_t)v * KP + fb) = pk;
    }
}

// ---------------- final: out = sigmoid(H @ H^T), fp8 MFMA, symmetric triangle ----------------
__global__ __launch_bounds__(256) void k_gemm_sig(const unsigned char* __restrict__ Hm,
                                                  float* __restrict__ out) {
    const int bx = blockIdx.x, by = blockIdx.y;
    if (bx < by) return;   // C symmetric: compute by<=bx, write both tiles
    __shared__ __align__(16) unsigned char As[128 * 32];   // 128 rows x 32 fp8
    __shared__ __align__(16) unsigned char Bs[128 * 32];
    const int tid = threadIdx.x;
    const int wave = tid >> 6;
    const int lane = tid & 63;
    const int rowA0 = by * 128;
    const int rowB0 = bx * 128;

    // staging: lane covers row (wave*32 + lane/2), 16-byte half (lane&1)
    const int sRow = wave * 32 + (lane >> 1);
    const int sOff = (lane & 1) * 16;
    const unsigned char* gA = Hm + (size_t)(rowA0 + sRow) * KP + sOff;
    const unsigned char* gB = Hm + (size_t)(rowB0 + sRow) * KP + sOff;
    const int ldsOff = wave * 1024 + lane * 16;

    f32x4 acc[4][4] = {};

    const int wrow = wave >> 1, wcol = wave & 1;
    const int r = lane & 15, q = lane >> 4;

    for (int kt = 0; kt < KP / 32; ++kt) {
        const int k0 = kt * 32;
        __builtin_amdgcn_global_load_lds(
            (const __attribute__((address_space(1))) void*)(gA + k0),
            (__attribute__((address_space(3))) void*)(As + ldsOff), 16, 0, 0);
        __builtin_amdgcn_global_load_lds(
            (const __attribute__((address_space(1))) void*)(gB + k0),
            (__attribute__((address_space(3))) void*)(Bs + ldsOff), 16, 0, 0);
        __syncthreads();
        long af[4], bfr[4];
#pragma unroll
        for (int mi = 0; mi < 4; ++mi)
            af[mi] = *(const long*)(As + (wrow * 64 + mi * 16 + r) * 32 + q * 8);
#pragma unroll
        for (int ni = 0; ni < 4; ++ni)
            bfr[ni] = *(const long*)(Bs + (wcol * 64 + ni * 16 + r) * 32 + q * 8);
#pragma unroll
        for (int mi = 0; mi < 4; ++mi)
#pragma unroll
            for (int ni = 0; ni < 4; ++ni)
                acc[mi][ni] = __builtin_amdgcn_mfma_f32_16x16x32_fp8_fp8(af[mi], bfr[ni], acc[mi][ni], 0, 0, 0);
        __syncthreads();
    }

    // epilogue. C/D layout: col=lane&15, row=(lane>>4)*4+reg. N%4==0, row0%4==0.
#pragma unroll
    for (int mi = 0; mi < 4; ++mi) {
        const int row0 = rowA0 + wrow * 64 + mi * 16 + q * 4;
#pragma unroll
        for (int ni = 0; ni < 4; ++ni) {
            const int col = rowB0 + wcol * 64 + ni * 16 + r;
            if (col < NNODES && row0 < NNODES) {
                f32x4 s;
#pragma unroll
                for (int r2 = 0; r2 < 4; ++r2)
                    s[r2] = 1.f / (1.f + __expf(-acc[mi][ni][r2]));
#pragma unroll
                for (int r2 = 0; r2 < 4; ++r2)
                    out[(size_t)(row0 + r2) * NNODES + col] = s[r2];
                if (bx != by)   // mirrored tile: contiguous float4 store
                    *(f32x4*)(out + (size_t)col * NNODES + row0) = s;
            }
        }
    }
}

// ---------------- edge_index passthrough as f32 ----------------
__global__ void k_edges(const int* __restrict__ ei, float* __restrict__ outbase) {
    int i = blockIdx.x * blockDim.x + threadIdx.x;
    if (i < 2 * NEDGES)
        outbase[(size_t)NNODES * (size_t)NNODES + (size_t)i] = (float)ei[i];
}

extern "C" void kernel_launch(void* const* d_in, const int* in_sizes, int n_in,
                              void* d_out, int out_size, void* d_ws, size_t ws_size,
                              hipStream_t stream) {
    const bf16_t* x   = (const bf16_t*)d_in[0];
    const int*    ei  = (const int*)d_in[1];
    const bf16_t* W1  = (const bf16_t*)d_in[2];
    const bf16_t* as1 = (const bf16_t*)d_in[3];
    const bf16_t* ad1 = (const bf16_t*)d_in[4];
    const bf16_t* b1  = (const bf16_t*)d_in[5];
    const bf16_t* W2  = (const bf16_t*)d_in[6];
    const bf16_t* as2 = (const bf16_t*)d_in[7];
    const bf16_t* ad2 = (const bf16_t*)d_in[8];
    const bf16_t* b2  = (const bf16_t*)d_in[9];
    float* out = (float*)d_out;   // output 0 f32 [N][N], output 1 f32 [2][E]

    // Scratch lives inside d_out's adjacency region (576 MB f32), dead until
    // k_gemm_sig overwrites it. Only h2 (read during final GEMM) is in d_ws.
    char* obuf = (char*)d_out;
    size_t off = 0;
    auto carve = [&](size_t bytes) {
        char* p = obuf + off;
        off += (bytes + 255) & ~(size_t)255;
        return p;
    };
    float* h1pre  = (float*)carve((size_t)NNODES * FHID * 4);
    float* al1    = (float*)carve((size_t)NNODES * 4);
    float* ar1    = (float*)carve((size_t)NNODES * 4);
    float* h1     = (float*)carve((size_t)NNODES * FHID * 4);
    float* al2    = (float*)carve((size_t)NNODES * 4);
    float* ar2    = (float*)carve((size_t)NNODES * 4);
    int*   deg    = (int*)carve((size_t)NNODES * 4);
    int*   rowptr = (int*)carve((size_t)(NNODES + 1) * 4);
    int*   cursor = (int*)carve((size_t)NNODES * 4);
    int*   csrc   = (int*)carve((size_t)NETOT * 4);
    unsigned char* h2pre = (unsigned char*)carve((size_t)NNODES * KP);  // fp8
    unsigned char* h2 = (unsigned char*)d_ws;   // [MP][KP] fp8 = 17.3 MB
    (void)ws_size; (void)in_sizes; (void)n_in; (void)out_size;

    hipLaunchKernelGGL(k_init,    dim3(256), dim3(256), 0, stream, deg, h2);
    hipLaunchKernelGGL(k_count,   dim3((NEDGES + 255) / 256), dim3(256), 0, stream, ei, deg);
    hipLaunchKernelGGL(k_scan,    dim3(1), dim3(1024), 0, stream, deg, rowptr);
    hipLaunchKernelGGL(k_cursor,  dim3((NNODES + 255) / 256), dim3(256), 0, stream, rowptr, cursor);
    hipLaunchKernelGGL(k_fill,    dim3((NETOT + 255) / 256), dim3(256), 0, stream, ei, cursor, csrc);
    hipLaunchKernelGGL(k_linear1, dim3((NNODES + 255) / 256), dim3(256), 0, stream,
                       x, W1, as1, ad1, h1pre, al1, ar1);
    hipLaunchKernelGGL(k_agg1,    dim3(NNODES), dim3(64), 0, stream,
                       h1pre, al1, ar1, rowptr, csrc, b1, h1);
    hipLaunchKernelGGL(k_linear2, dim3(NNODES / 4), dim3(256), 0, stream,
                       h1, W2, as2, ad2, h2pre, al2, ar2);
    hipLaunchKernelGGL(k_agg2,    dim3(NNODES), dim3(256), 0, stream,
                       h2pre, al2, ar2, rowptr, csrc, b2, h2);
    hipLaunchKernelGGL(k_gemm_sig, dim3(MP / 128, MP / 128), dim3(256), 0, stream, h2, out);
    hipLaunchKernelGGL(k_edges,   dim3((2 * NEDGES + 255) / 256), dim3(256), 0, stream, ei, out);
}

// Round 6
// 1172.775 us; speedup vs baseline: 1.0719x; 1.0719x over previous
//
#include <hip/hip_runtime.h>
#include <hip/hip_bf16.h>

#define NNODES 12000
#define NEDGES 384000
#define NETOT  (NEDGES + NNODES)   /* 396000 incl self-loops */
#define FIN    4
#define FHID   50
#define FOUT   1433
#define KP     1440                /* FOUT padded to multiple of 32 */
#define MP     12032               /* NNODES padded to multiple of 128 */
#define NTILE  (MP / 128)          /* 94 */
#define NTRI   (NTILE * (NTILE + 1) / 2)   /* 4465 upper-triangle tiles */
#define NEG_SLOPE 0.2f

typedef __hip_bfloat16 bf16_t;
typedef __bf16 bf16x8 __attribute__((ext_vector_type(8)));
typedef float f32x4 __attribute__((ext_vector_type(4)));
typedef float f32x2 __attribute__((ext_vector_type(2)));

__device__ __forceinline__ float  b2f(bf16_t h) { return __bfloat162float(h); }
__device__ __forceinline__ bf16_t f2b(float f)  { return __float2bfloat16(f); }
__device__ __forceinline__ unsigned short f2bu(float f) { bf16_t h = f2b(f); return *(unsigned short*)&h; }

// ---------------- init: deg=1 (self loop), zero pad rows of h2 (bf16) ----------------
__global__ void k_init(int* __restrict__ deg, bf16_t* __restrict__ h2) {
    int i = blockIdx.x * blockDim.x + threadIdx.x;
    int stride = gridDim.x * blockDim.x;
    for (int v = i; v < NNODES; v += stride) deg[v] = 1;
    const size_t padN = (size_t)(MP - NNODES) * KP;
    for (size_t t = i; t < padN; t += stride) h2[(size_t)NNODES * KP + t] = f2b(0.f);
}

// ---------------- count real edges by dst ----------------
__global__ void k_count(const int* __restrict__ ei, int* __restrict__ deg) {
    int i = blockIdx.x * blockDim.x + threadIdx.x;
    if (i < NEDGES) atomicAdd(&deg[ei[NEDGES + i]], 1);
}

// ---------------- single-block exclusive scan -> rowptr[N+1] ----------------
__global__ __launch_bounds__(1024) void k_scan(const int* __restrict__ deg, int* __restrict__ rowptr) {
    __shared__ int sd[1024];
    __shared__ int carry;
    int tid = threadIdx.x;
    if (tid == 0) { carry = 0; rowptr[0] = 0; }
    __syncthreads();
    for (int base = 0; base < NNODES; base += 1024) {
        int v = (base + tid < NNODES) ? deg[base + tid] : 0;
        sd[tid] = v;
        __syncthreads();
        for (int off = 1; off < 1024; off <<= 1) {
            int t = (tid >= off) ? sd[tid - off] : 0;
            __syncthreads();
            sd[tid] += t;
            __syncthreads();
        }
        int inc = sd[tid] + carry;
        if (base + tid < NNODES) rowptr[base + tid + 1] = inc;
        __syncthreads();
        if (tid == 1023) carry = sd[1023] + carry;
        __syncthreads();
    }
}

__global__ void k_cursor(const int* __restrict__ rowptr, int* __restrict__ cursor) {
    int i = blockIdx.x * blockDim.x + threadIdx.x;
    if (i < NNODES) cursor[i] = rowptr[i];
}

// ---------------- fill CSR src lists (incl self loops) ----------------
__global__ void k_fill(const int* __restrict__ ei, int* __restrict__ cursor, int* __restrict__ csrc) {
    int i = blockIdx.x * blockDim.x + threadIdx.x;
    if (i < NETOT) {
        int s, d;
        if (i < NEDGES) { s = ei[i]; d = ei[NEDGES + i]; }
        else            { s = d = i - NEDGES; }
        int pos = atomicAdd(&cursor[d], 1);
        csrc[pos] = s;
    }
}

// ---------------- layer1 linear: h1pre = x @ W1, al1/ar1 logit parts ----------------
__global__ __launch_bounds__(256) void k_linear1(
        const bf16_t* __restrict__ x, const bf16_t* __restrict__ W1,
        const bf16_t* __restrict__ as1, const bf16_t* __restrict__ ad1,
        float* __restrict__ h1pre, float* __restrict__ al, float* __restrict__ ar) {
    __shared__ float sW[FIN * FHID];
    __shared__ float sa[FHID], sdl[FHID];
    int tid = threadIdx.x;
    if (tid < FIN * FHID) sW[tid] = b2f(W1[tid]);
    if (tid < FHID) { sa[tid] = b2f(as1[tid]); sdl[tid] = b2f(ad1[tid]); }
    __syncthreads();
    int i = blockIdx.x * 256 + tid;
    if (i >= NNODES) return;
    float x0 = b2f(x[i * 4 + 0]), x1 = b2f(x[i * 4 + 1]);
    float x2 = b2f(x[i * 4 + 2]), x3 = b2f(x[i * 4 + 3]);
    float hal = 0.f, har = 0.f;
    for (int j = 0; j < FHID; ++j) {
        float h = x0 * sW[j] + x1 * sW[FHID + j] + x2 * sW[2 * FHID + j] + x3 * sW[3 * FHID + j];
        h1pre[(size_t)i * FHID + j] = h;
        hal += h * sa[j];
        har += h * sdl[j];
    }
    al[i] = hal; ar[i] = har;
}

// ---------------- layer1 softmax-aggregate (one wave per dst) ----------------
__global__ __launch_bounds__(64) void k_agg1(
        const float* __restrict__ h1pre, const float* __restrict__ al, const float* __restrict__ ar,
        const int* __restrict__ rowptr, const int* __restrict__ csrc,
        const bf16_t* __restrict__ b1, float* __restrict__ h1) {
    int v = blockIdx.x, tid = threadIdx.x;
    int s0 = rowptr[v], s1 = rowptr[v + 1];
    float arv = ar[v];
    float m = -1e30f;
    for (int e = s0 + tid; e < s1; e += 64) {
        float l = al[csrc[e]] + arv;
        l = l > 0.f ? l : NEG_SLOPE * l;
        m = fmaxf(m, l);
    }
#pragma unroll
    for (int off = 32; off; off >>= 1) m = fmaxf(m, __shfl_xor(m, off, 64));
    __shared__ float sw[64];
    __shared__ int ssrc[64];
    float acc = 0.f, ssum = 0.f;
    for (int base = s0; base < s1; base += 64) {
        int e = base + tid;
        float w = 0.f; int si = 0;
        if (e < s1) {
            si = csrc[e];
            float l = al[si] + arv;
            l = l > 0.f ? l : NEG_SLOPE * l;
            w = __expf(l - m);
        }
        ssum += w;
        sw[tid] = w; ssrc[tid] = si;
        __syncthreads();
        int cnt = min(64, s1 - base);
        if (tid < FHID) {
#pragma unroll 4
            for (int j = 0; j < cnt; ++j)
                acc += sw[j] * h1pre[(size_t)ssrc[j] * FHID + tid];
        }
        __syncthreads();
    }
#pragma unroll
    for (int off = 32; off; off >>= 1) ssum += __shfl_xor(ssum, off, 64);
    if (tid < FHID) {
        float o = acc / ssum + b2f(b1[tid]);
        h1[(size_t)v * FHID + tid] = fmaxf(o, 0.f);
    }
}

// ---------------- layer2 linear: 4 nodes/block, h2pre (fp8 e4m3) = h1 @ W2, al2/ar2 ----------------
__global__ __launch_bounds__(256) void k_linear2(
        const float* __restrict__ h1, const bf16_t* __restrict__ W2,
        const bf16_t* __restrict__ as2, const bf16_t* __restrict__ ad2,
        unsigned char* __restrict__ h2pre, float* __restrict__ al2, float* __restrict__ ar2) {
    int v0 = blockIdx.x * 4, tid = threadIdx.x;
    __shared__ float sh[4][FHID];
    if (tid < 4 * FHID) sh[tid / FHID][tid % FHID] = h1[(size_t)v0 * FHID + tid];
    __syncthreads();
    float pal[4] = {0.f, 0.f, 0.f, 0.f}, par[4] = {0.f, 0.f, 0.f, 0.f};
#pragma unroll
    for (int i = 0; i < 3; ++i) {
        int f0 = i * 512 + 2 * tid;          // even feature index
        if (f0 < KP) {
            float d0[4] = {0.f, 0.f, 0.f, 0.f}, d1[4] = {0.f, 0.f, 0.f, 0.f};
            bool ok0 = f0 < FOUT, ok1 = f0 + 1 < FOUT;
            if (ok0) {
                int f1 = ok1 ? f0 + 1 : f0;  // safe aliased read when f0+1 OOB
#pragma unroll 10
                for (int k = 0; k < FHID; ++k) {
                    float w0 = b2f(W2[k * FOUT + f0]);
                    float w1 = b2f(W2[k * FOUT + f1]);
#pragma unroll
                    for (int c = 0; c < 4; ++c) {
                        d0[c] += sh[c][k] * w0;
                        d1[c] += sh[c][k] * w1;
                    }
                }
                if (!ok1) { d1[0] = d1[1] = d1[2] = d1[3] = 0.f; }
                float sa0 = b2f(as2[f0]), sd0 = b2f(ad2[f0]);
                float sa1 = ok1 ? b2f(as2[f0 + 1]) : 0.f;
                float sd1 = ok1 ? b2f(ad2[f0 + 1]) : 0.f;
#pragma unroll
                for (int c = 0; c < 4; ++c) {
                    pal[c] += d0[c] * sa0 + d1[c] * sa1;
                    par[c] += d0[c] * sd0 + d1[c] * sd1;
                }
            }
#pragma unroll
            for (int c = 0; c < 4; ++c) {
                int pk = __builtin_amdgcn_cvt_pk_fp8_f32(d0[c], d1[c], 0, false);
                *(unsigned short*)(h2pre + (size_t)(v0 + c) * KP + f0) = (unsigned short)pk;
            }
        }
    }
#pragma unroll
    for (int off = 32; off; off >>= 1)
#pragma unroll
        for (int c = 0; c < 4; ++c) {
            pal[c] += __shfl_xor(pal[c], off, 64);
            par[c] += __shfl_xor(par[c], off, 64);
        }
    __shared__ float rA[4][4], rB[4][4];
    int wave = tid >> 6, lane = tid & 63;
    if (lane == 0)
#pragma unroll
        for (int c = 0; c < 4; ++c) { rA[wave][c] = pal[c]; rB[wave][c] = par[c]; }
    __syncthreads();
    if (tid < 4) {
        al2[v0 + tid] = rA[0][tid] + rA[1][tid] + rA[2][tid] + rA[3][tid];
        ar2[v0 + tid] = rB[0][tid] + rB[1][tid] + rB[2][tid] + rB[3][tid];
    }
}

// ---------------- layer2 softmax-aggregate: fp8 uint2 gather (8 feats/lane), bf16 h2 out ----------------
__global__ __launch_bounds__(256) void k_agg2(
        const unsigned char* __restrict__ h2pre, const float* __restrict__ al, const float* __restrict__ ar,
        const int* __restrict__ rowptr, const int* __restrict__ csrc,
        const bf16_t* __restrict__ bias2, bf16_t* __restrict__ h2) {
    int v = blockIdx.x, tid = threadIdx.x;
    int s0 = rowptr[v], s1 = rowptr[v + 1];
    float arv = ar[v];
    float m = -1e30f;
    for (int e = s0 + tid; e < s1; e += 256) {
        float l = al[csrc[e]] + arv;
        l = l > 0.f ? l : NEG_SLOPE * l;
        m = fmaxf(m, l);
    }
#pragma unroll
    for (int off = 32; off; off >>= 1) m = fmaxf(m, __shfl_xor(m, off, 64));
    __shared__ float red[4];
    int wave = tid >> 6, lane = tid & 63;
    if (lane == 0) red[wave] = m;
    __syncthreads();
    m = fmaxf(fmaxf(red[0], red[1]), fmaxf(red[2], red[3]));
    __syncthreads();

    float acc[8] = {0.f, 0.f, 0.f, 0.f, 0.f, 0.f, 0.f, 0.f};
    float ssum = 0.f;
    __shared__ float sw[256];
    __shared__ int ssrc[256];
    const bool act = tid < (KP / 8);          // 180 lanes cover the 1440-B row
    for (int base = s0; base < s1; base += 256) {
        int e = base + tid;
        float w = 0.f; int si = 0;
        if (e < s1) {
            si = csrc[e];
            float l = al[si] + arv;
            l = l > 0.f ? l : NEG_SLOPE * l;
            w = __expf(l - m);
        }
        ssum += w;
        sw[tid] = w; ssrc[tid] = si;
        __syncthreads();
        int cnt = min(256, s1 - base);
        if (act) {
#pragma unroll 8
            for (int j = 0; j < cnt; ++j) {
                float wj = sw[j];
                const uint2* hp = (const uint2*)(h2pre + (size_t)ssrc[j] * KP);
                uint2 p = hp[tid];
                f32x2 e0 = __builtin_amdgcn_cvt_pk_f32_fp8(p.x, false);
                f32x2 e1 = __builtin_amdgcn_cvt_pk_f32_fp8(p.x, true);
                f32x2 e2 = __builtin_amdgcn_cvt_pk_f32_fp8(p.y, false);
                f32x2 e3 = __builtin_amdgcn_cvt_pk_f32_fp8(p.y, true);
                acc[0] += wj * e0.x; acc[1] += wj * e0.y;
                acc[2] += wj * e1.x; acc[3] += wj * e1.y;
                acc[4] += wj * e2.x; acc[5] += wj * e2.y;
                acc[6] += wj * e3.x; acc[7] += wj * e3.y;
            }
        }
        __syncthreads();
    }
#pragma unroll
    for (int off = 32; off; off >>= 1) ssum += __shfl_xor(ssum, off, 64);
    if (lane == 0) red[wave] = ssum;
    __syncthreads();
    float inv = 1.f / (red[0] + red[1] + red[2] + red[3]);

    if (act) {
        int fb = 8 * tid;
        unsigned short o[8];
#pragma unroll
        for (int t = 0; t < 8; ++t) {
            int f = fb + t;
            o[t] = f2bu((f < FOUT) ? fmaxf(acc[t] * inv + b2f(bias2[f]), 0.f) : 0.f);
        }
        uint4 pk;
        pk.x = (unsigned)o[0] | ((unsigned)o[1] << 16);
        pk.y = (unsigned)o[2] | ((unsigned)o[3] << 16);
        pk.z = (unsigned)o[4] | ((unsigned)o[5] << 16);
        pk.w = (unsigned)o[6] | ((unsigned)o[7] << 16);
        *(uint4*)(h2 + (size_t)v * KP + fb) = pk;
    }
}

// ---------------- final: out = sigmoid(H @ H^T), bf16 MFMA, 1-D triangular grid ----------------
__global__ __launch_bounds__(256) void k_gemm_sig(const bf16_t* __restrict__ Hm,
                                                  float* __restrict__ out) {
    // decode linear tile id -> (by, bx) with bx >= by
    int t = blockIdx.x;
    int by = (int)((2 * NTILE + 1 - sqrtf((float)(2 * NTILE + 1) * (2 * NTILE + 1) - 8.0f * t)) * 0.5f);
    if (by < 0) by = 0;
    if (by > NTILE - 1) by = NTILE - 1;
    // start(b) = b*NTILE - b*(b-1)/2
    while (by + 1 < NTILE && (by + 1) * NTILE - ((by + 1) * by) / 2 <= t) ++by;
    while (by > 0 && by * NTILE - (by * (by - 1)) / 2 > t) --by;
    int bx = by + (t - (by * NTILE - (by * (by - 1)) / 2));

    __shared__ __align__(16) bf16_t As[128 * 32];
    __shared__ __align__(16) bf16_t Bs[128 * 32];
    const int tid = threadIdx.x;
    const int wave = tid >> 6;
    const int lane = tid & 63;
    const int rowA0 = by * 128;
    const int rowB0 = bx * 128;

    // staging: lane covers LDS row (c*64 + wave*16 + lane/4), k-slot (lane&3), data slot XOR-swizzled
    const int sRow  = wave * 16 + (lane >> 2);
    const int sSlot = (lane & 3) ^ ((lane >> 2) & 3);
    const bf16_t* gA = Hm + (size_t)(rowA0 + sRow) * KP + sSlot * 8;
    const bf16_t* gB = Hm + (size_t)(rowB0 + sRow) * KP + sSlot * 8;

    f32x4 acc[4][4] = {};

    const int wrow = wave >> 1, wcol = wave & 1;
    const int r = lane & 15, q = lane >> 4;
    const int rslot = q ^ (r & 3);            // data for k-slot q is at LDS slot q^(row&3)
    const __bf16* Asb = (const __bf16*)As;
    const __bf16* Bsb = (const __bf16*)Bs;

    for (int kt = 0; kt < KP / 32; ++kt) {
        const int k0 = kt * 32;
#pragma unroll
        for (int c = 0; c < 2; ++c) {
            __builtin_amdgcn_global_load_lds(
                (const __attribute__((address_space(1))) void*)(gA + (size_t)c * 64 * KP + k0),
                (__attribute__((address_space(3))) void*)((char*)As + c * 4096 + wave * 1024),
                16, 0, 0);
            __builtin_amdgcn_global_load_lds(
                (const __attribute__((address_space(1))) void*)(gB + (size_t)c * 64 * KP + k0),
                (__attribute__((address_space(3))) void*)((char*)Bs + c * 4096 + wave * 1024),
                16, 0, 0);
        }
        __syncthreads();
        bf16x8 af[4], bfr[4];
#pragma unroll
        for (int mi = 0; mi < 4; ++mi)
            af[mi] = *(const bf16x8*)(Asb + ((wrow * 64 + mi * 16 + r) * 32 + rslot * 8));
#pragma unroll
        for (int ni = 0; ni < 4; ++ni)
            bfr[ni] = *(const bf16x8*)(Bsb + ((wcol * 64 + ni * 16 + r) * 32 + rslot * 8));
#pragma unroll
        for (int mi = 0; mi < 4; ++mi)
#pragma unroll
            for (int ni = 0; ni < 4; ++ni)
                acc[mi][ni] = __builtin_amdgcn_mfma_f32_16x16x32_bf16(af[mi], bfr[ni], acc[mi][ni], 0, 0, 0);
        __syncthreads();
    }

    // epilogue. C/D layout: col=lane&15, row=(lane>>4)*4+reg. N%4==0, row0%4==0.
#pragma unroll
    for (int mi = 0; mi < 4; ++mi) {
        const int row0 = rowA0 + wrow * 64 + mi * 16 + q * 4;
#pragma unroll
        for (int ni = 0; ni < 4; ++ni) {
            const int col = rowB0 + wcol * 64 + ni * 16 + r;
            if (col < NNODES && row0 < NNODES) {
                f32x4 s;
#pragma unroll
                for (int r2 = 0; r2 < 4; ++r2)
                    s[r2] = 1.f / (1.f + __expf(-acc[mi][ni][r2]));
#pragma unroll
                for (int r2 = 0; r2 < 4; ++r2)
                    out[(size_t)(row0 + r2) * NNODES + col] = s[r2];
                if (bx != by)   // mirrored tile: contiguous float4 store
                    *(f32x4*)(out + (size_t)col * NNODES + row0) = s;
            }
        }
    }
}

// ---------------- edge_index passthrough as f32 ----------------
__global__ void k_edges(const int* __restrict__ ei, float* __restrict__ outbase) {
    int i = blockIdx.x * blockDim.x + threadIdx.x;
    if (i < 2 * NEDGES)
        outbase[(size_t)NNODES * (size_t)NNODES + (size_t)i] = (float)ei[i];
}

extern "C" void kernel_launch(void* const* d_in, const int* in_sizes, int n_in,
                              void* d_out, int out_size, void* d_ws, size_t ws_size,
                              hipStream_t stream) {
    const bf16_t* x   = (const bf16_t*)d_in[0];
    const int*    ei  = (const int*)d_in[1];
    const bf16_t* W1  = (const bf16_t*)d_in[2];
    const bf16_t* as1 = (const bf16_t*)d_in[3];
    const bf16_t* ad1 = (const bf16_t*)d_in[4];
    const bf16_t* b1  = (const bf16_t*)d_in[5];
    const bf16_t* W2  = (const bf16_t*)d_in[6];
    const bf16_t* as2 = (const bf16_t*)d_in[7];
    const bf16_t* ad2 = (const bf16_t*)d_in[8];
    const bf16_t* b2  = (const bf16_t*)d_in[9];
    float* out = (float*)d_out;   // output 0 f32 [N][N], output 1 f32 [2][E]

    // Scratch lives inside d_out's adjacency region (576 MB f32), dead until
    // k_gemm_sig overwrites it. Only h2 (read during final GEMM) is in d_ws.
    char* obuf = (char*)d_out;
    size_t off = 0;
    auto carve = [&](size_t bytes) {
        char* p = obuf + off;
        off += (bytes + 255) & ~(size_t)255;
        return p;
    };
    float* h1pre  = (float*)carve((size_t)NNODES * FHID * 4);
    float* al1    = (float*)carve((size_t)NNODES * 4);
    float* ar1    = (float*)carve((size_t)NNODES * 4);
    float* h1     = (float*)carve((size_t)NNODES * FHID * 4);
    float* al2    = (float*)carve((size_t)NNODES * 4);
    float* ar2    = (float*)carve((size_t)NNODES * 4);
    int*   deg    = (int*)carve((size_t)NNODES * 4);
    int*   rowptr = (int*)carve((size_t)(NNODES + 1) * 4);
    int*   cursor = (int*)carve((size_t)NNODES * 4);
    int*   csrc   = (int*)carve((size_t)NETOT * 4);
    unsigned char* h2pre = (unsigned char*)carve((size_t)NNODES * KP);  // fp8
    bf16_t* h2 = (bf16_t*)d_ws;   // [MP][KP] bf16 = 34.65 MB
    (void)ws_size; (void)in_sizes; (void)n_in; (void)out_size;

    hipLaunchKernelGGL(k_init,    dim3(256), dim3(256), 0, stream, deg, h2);
    hipLaunchKernelGGL(k_count,   dim3((NEDGES + 255) / 256), dim3(256), 0, stream, ei, deg);
    hipLaunchKernelGGL(k_scan,    dim3(1), dim3(1024), 0, stream, deg, rowptr);
    hipLaunchKernelGGL(k_cursor,  dim3((NNODES + 255) / 256), dim3(256), 0, stream, rowptr, cursor);
    hipLaunchKernelGGL(k_fill,    dim3((NETOT + 255) / 256), dim3(256), 0, stream, ei, cursor, csrc);
    hipLaunchKernelGGL(k_linear1, dim3((NNODES + 255) / 256), dim3(256), 0, stream,
                       x, W1, as1, ad1, h1pre, al1, ar1);
    hipLaunchKernelGGL(k_agg1,    dim3(NNODES), dim3(64), 0, stream,
                       h1pre, al1, ar1, rowptr, csrc, b1, h1);
    hipLaunchKernelGGL(k_linear2, dim3(NNODES / 4), dim3(256), 0, stream,
                       h1, W2, as2, ad2, h2pre, al2, ar2);
    hipLaunchKernelGGL(k_agg2,    dim3(NNODES), dim3(256), 0, stream,
                       h2pre, al2, ar2, rowptr, csrc, b2, h2);
    hipLaunchKernelGGL(k_gemm_sig, dim3(NTRI), dim3(256), 0, stream, h2, out);
    hipLaunchKernelGGL(k_edges,   dim3((2 * NEDGES + 255) / 256), dim3(256), 0, stream, ei, out);
}

// Round 7
// 1150.333 us; speedup vs baseline: 1.0928x; 1.0195x over previous
//
#include <hip/hip_runtime.h>
#include <hip/hip_bf16.h>

#define NNODES 12000
#define NEDGES 384000
#define NETOT  (NEDGES + NNODES)   /* 396000 incl self-loops */
#define FIN    4
#define FHID   50
#define FOUT   1433
#define KP     1440                /* FOUT padded to multiple of 32 */
#define MP     12032               /* NNODES padded to multiple of 128 */
#define NTILE  (MP / 128)          /* 94 */
#define NTRI   (NTILE * (NTILE + 1) / 2)   /* 4465 upper-triangle tiles */
#define NEG_SLOPE 0.2f

typedef __hip_bfloat16 bf16_t;
typedef __bf16 bf16x8 __attribute__((ext_vector_type(8)));
typedef float f32x4 __attribute__((ext_vector_type(4)));
typedef float f32x2 __attribute__((ext_vector_type(2)));

__device__ __forceinline__ float  b2f(bf16_t h) { return __bfloat162float(h); }
__device__ __forceinline__ bf16_t f2b(float f)  { return __float2bfloat16(f); }
__device__ __forceinline__ unsigned short f2bu(float f) { bf16_t h = f2b(f); return *(unsigned short*)&h; }

// ---------------- init: deg=1 (self loop), zero pad rows of h2 (bf16) ----------------
__global__ void k_init(int* __restrict__ deg, bf16_t* __restrict__ h2) {
    int i = blockIdx.x * blockDim.x + threadIdx.x;
    int stride = gridDim.x * blockDim.x;
    for (int v = i; v < NNODES; v += stride) deg[v] = 1;
    const size_t padN = (size_t)(MP - NNODES) * KP;
    for (size_t t = i; t < padN; t += stride) h2[(size_t)NNODES * KP + t] = f2b(0.f);
}

// ---------------- count real edges by dst ----------------
__global__ void k_count(const int* __restrict__ ei, int* __restrict__ deg) {
    int i = blockIdx.x * blockDim.x + threadIdx.x;
    if (i < NEDGES) atomicAdd(&deg[ei[NEDGES + i]], 1);
}

// ---------------- single-block shfl exclusive scan -> rowptr[N+1] + cursor[N] ----------------
// 12 elems/thread blocked; wave shfl-scan; 16-wave LDS combine; 2 barriers total.
__global__ __launch_bounds__(1024) void k_scan(const int* __restrict__ deg,
                                               int* __restrict__ rowptr,
                                               int* __restrict__ cursor) {
    __shared__ int wsum[16];
    const int tid = threadIdx.x, lane = tid & 63, wv = tid >> 6;
    const int base = tid * 12;
    int pref[12];
    int s = 0;
#pragma unroll
    for (int u = 0; u < 12; ++u) {
        int idx = base + u;
        int d = (idx < NNODES) ? deg[idx] : 0;
        pref[u] = s;
        s += d;
    }
    int sc = s;   // inclusive wave scan of per-thread sums
#pragma unroll
    for (int o = 1; o < 64; o <<= 1) {
        int t2 = __shfl_up(sc, o, 64);
        if (lane >= o) sc += t2;
    }
    if (lane == 63) wsum[wv] = sc;
    __syncthreads();
    if (wv == 0 && lane < 16) {
        int mine = wsum[lane];
        int scw = mine;
#pragma unroll
        for (int o = 1; o < 16; o <<= 1) {
            int t3 = __shfl_up(scw, o, 64);
            if (lane >= o) scw += t3;
        }
        wsum[lane] = scw - mine;   // exclusive wave prefix
    }
    __syncthreads();
    const int pre = wsum[wv] + (sc - s);   // exclusive prefix of this thread
#pragma unroll
    for (int u = 0; u < 12; ++u) {
        int idx = base + u;
        if (idx < NNODES) {
            int p = pre + pref[u];
            rowptr[idx] = p;
            cursor[idx] = p;
        }
    }
    if (tid == 1023) rowptr[NNODES] = pre + s;   // == NETOT
}

// ---------------- fill CSR src lists (incl self loops) + edge passthrough ----------------
__global__ void k_fill(const int* __restrict__ ei, int* __restrict__ cursor,
                       int* __restrict__ csrc, float* __restrict__ outbase) {
    int i = blockIdx.x * blockDim.x + threadIdx.x;
    if (i < NETOT) {
        int s, d;
        if (i < NEDGES) { s = ei[i]; d = ei[NEDGES + i]; }
        else            { s = d = i - NEDGES; }
        int pos = atomicAdd(&cursor[d], 1);
        csrc[pos] = s;
    }
    if (i < 2 * NEDGES)
        outbase[(size_t)NNODES * (size_t)NNODES + (size_t)i] = (float)ei[i];
}

// ---------------- layer1 linear: h1pre = x @ W1, al1/ar1 logit parts ----------------
__global__ __launch_bounds__(256) void k_linear1(
        const bf16_t* __restrict__ x, const bf16_t* __restrict__ W1,
        const bf16_t* __restrict__ as1, const bf16_t* __restrict__ ad1,
        float* __restrict__ h1pre, float* __restrict__ al, float* __restrict__ ar) {
    __shared__ float sW[FIN * FHID];
    __shared__ float sa[FHID], sdl[FHID];
    int tid = threadIdx.x;
    if (tid < FIN * FHID) sW[tid] = b2f(W1[tid]);
    if (tid < FHID) { sa[tid] = b2f(as1[tid]); sdl[tid] = b2f(ad1[tid]); }
    __syncthreads();
    int i = blockIdx.x * 256 + tid;
    if (i >= NNODES) return;
    float x0 = b2f(x[i * 4 + 0]), x1 = b2f(x[i * 4 + 1]);
    float x2 = b2f(x[i * 4 + 2]), x3 = b2f(x[i * 4 + 3]);
    float hal = 0.f, har = 0.f;
    for (int j = 0; j < FHID; ++j) {
        float h = x0 * sW[j] + x1 * sW[FHID + j] + x2 * sW[2 * FHID + j] + x3 * sW[3 * FHID + j];
        h1pre[(size_t)i * FHID + j] = h;
        hal += h * sa[j];
        har += h * sdl[j];
    }
    al[i] = hal; ar[i] = har;
}

// ---------------- layer1 softmax-aggregate: wave-per-node, no max pass, shfl broadcast ----------------
__global__ __launch_bounds__(256) void k_agg1(
        const float* __restrict__ h1pre, const float* __restrict__ al, const float* __restrict__ ar,
        const int* __restrict__ rowptr, const int* __restrict__ csrc,
        const bf16_t* __restrict__ b1, float* __restrict__ h1) {
    const int wv = threadIdx.x >> 6, lane = threadIdx.x & 63;
    const int v = blockIdx.x * 4 + wv;        // NNODES % 4 == 0
    const int s0 = rowptr[v], s1 = rowptr[v + 1];
    const float arv = ar[v];
    float acc = 0.f, ssum = 0.f;
    for (int base = s0; base < s1; base += 64) {
        int e = base + lane;
        float w = 0.f; int si = 0;
        if (e < s1) {
            si = csrc[e];
            float l = al[si] + arv;
            l = l > 0.f ? l : NEG_SLOPE * l;
            w = __expf(l);                     // softmax is shift-invariant; |l| small
        }
        ssum += w;
        int cnt = min(64, s1 - base);
#pragma unroll 4
        for (int j = 0; j < cnt; ++j) {
            float wj = __shfl(w, j, 64);
            int   sj = __shfl(si, j, 64);
            if (lane < FHID) acc += wj * h1pre[(size_t)sj * FHID + lane];
        }
    }
#pragma unroll
    for (int o = 32; o; o >>= 1) ssum += __shfl_xor(ssum, o, 64);
    if (lane < FHID) {
        float o2 = acc / ssum + b2f(b1[lane]);
        h1[(size_t)v * FHID + lane] = fmaxf(o2, 0.f);
    }
}

// ---------------- layer2 linear: 4 nodes/block, h2pre (fp8 e4m3) = h1 @ W2, al2/ar2 ----------------
__global__ __launch_bounds__(256) void k_linear2(
        const float* __restrict__ h1, const bf16_t* __restrict__ W2,
        const bf16_t* __restrict__ as2, const bf16_t* __restrict__ ad2,
        unsigned char* __restrict__ h2pre, float* __restrict__ al2, float* __restrict__ ar2) {
    int v0 = blockIdx.x * 4, tid = threadIdx.x;
    __shared__ float sh[4][FHID];
    if (tid < 4 * FHID) sh[tid / FHID][tid % FHID] = h1[(size_t)v0 * FHID + tid];
    __syncthreads();
    float pal[4] = {0.f, 0.f, 0.f, 0.f}, par[4] = {0.f, 0.f, 0.f, 0.f};
#pragma unroll
    for (int i = 0; i < 3; ++i) {
        int f0 = i * 512 + 2 * tid;          // even feature index
        if (f0 < KP) {
            float d0[4] = {0.f, 0.f, 0.f, 0.f}, d1[4] = {0.f, 0.f, 0.f, 0.f};
            bool ok0 = f0 < FOUT, ok1 = f0 + 1 < FOUT;
            if (ok0) {
                int f1 = ok1 ? f0 + 1 : f0;  // safe aliased read when f0+1 OOB
#pragma unroll 10
                for (int k = 0; k < FHID; ++k) {
                    float w0 = b2f(W2[k * FOUT + f0]);
                    float w1 = b2f(W2[k * FOUT + f1]);
#pragma unroll
                    for (int c = 0; c < 4; ++c) {
                        d0[c] += sh[c][k] * w0;
                        d1[c] += sh[c][k] * w1;
                    }
                }
                if (!ok1) { d1[0] = d1[1] = d1[2] = d1[3] = 0.f; }
                float sa0 = b2f(as2[f0]), sd0 = b2f(ad2[f0]);
                float sa1 = ok1 ? b2f(as2[f0 + 1]) : 0.f;
                float sd1 = ok1 ? b2f(ad2[f0 + 1]) : 0.f;
#pragma unroll
                for (int c = 0; c < 4; ++c) {
                    pal[c] += d0[c] * sa0 + d1[c] * sa1;
                    par[c] += d0[c] * sd0 + d1[c] * sd1;
                }
            }
#pragma unroll
            for (int c = 0; c < 4; ++c) {
                int pk = __builtin_amdgcn_cvt_pk_fp8_f32(d0[c], d1[c], 0, false);
                *(unsigned short*)(h2pre + (size_t)(v0 + c) * KP + f0) = (unsigned short)pk;
            }
        }
    }
#pragma unroll
    for (int off = 32; off; off >>= 1)
#pragma unroll
        for (int c = 0; c < 4; ++c) {
            pal[c] += __shfl_xor(pal[c], off, 64);
            par[c] += __shfl_xor(par[c], off, 64);
        }
    __shared__ float rA[4][4], rB[4][4];
    int wave = tid >> 6, lane = tid & 63;
    if (lane == 0)
#pragma unroll
        for (int c = 0; c < 4; ++c) { rA[wave][c] = pal[c]; rB[wave][c] = par[c]; }
    __syncthreads();
    if (tid < 4) {
        al2[v0 + tid] = rA[0][tid] + rA[1][tid] + rA[2][tid] + rA[3][tid];
        ar2[v0 + tid] = rB[0][tid] + rB[1][tid] + rB[2][tid] + rB[3][tid];
    }
}

// ---------------- layer2 softmax-aggregate: fp8 gather, no max pass, bf16 h2 out ----------------
__global__ __launch_bounds__(256) void k_agg2(
        const unsigned char* __restrict__ h2pre, const float* __restrict__ al, const float* __restrict__ ar,
        const int* __restrict__ rowptr, const int* __restrict__ csrc,
        const bf16_t* __restrict__ bias2, bf16_t* __restrict__ h2) {
    int v = blockIdx.x, tid = threadIdx.x;
    int s0 = rowptr[v], s1 = rowptr[v + 1];
    float arv = ar[v];
    int wave = tid >> 6, lane = tid & 63;

    float acc[8] = {0.f, 0.f, 0.f, 0.f, 0.f, 0.f, 0.f, 0.f};
    float ssum = 0.f;
    __shared__ float sw[256];
    __shared__ int ssrc[256];
    __shared__ float red[4];
    const bool act = tid < (KP / 8);          // 180 lanes cover the 1440-B row
    for (int base = s0; base < s1; base += 256) {
        int e = base + tid;
        float w = 0.f; int si = 0;
        if (e < s1) {
            si = csrc[e];
            float l = al[si] + arv;
            l = l > 0.f ? l : NEG_SLOPE * l;
            w = __expf(l);                    // shift-invariant; |l| small
        }
        ssum += w;
        sw[tid] = w; ssrc[tid] = si;
        __syncthreads();
        int cnt = min(256, s1 - base);
        if (act) {
#pragma unroll 8
            for (int j = 0; j < cnt; ++j) {
                float wj = sw[j];
                const uint2* hp = (const uint2*)(h2pre + (size_t)ssrc[j] * KP);
                uint2 p = hp[tid];
                f32x2 e0 = __builtin_amdgcn_cvt_pk_f32_fp8(p.x, false);
                f32x2 e1 = __builtin_amdgcn_cvt_pk_f32_fp8(p.x, true);
                f32x2 e2 = __builtin_amdgcn_cvt_pk_f32_fp8(p.y, false);
                f32x2 e3 = __builtin_amdgcn_cvt_pk_f32_fp8(p.y, true);
                acc[0] += wj * e0.x; acc[1] += wj * e0.y;
                acc[2] += wj * e1.x; acc[3] += wj * e1.y;
                acc[4] += wj * e2.x; acc[5] += wj * e2.y;
                acc[6] += wj * e3.x; acc[7] += wj * e3.y;
            }
        }
        __syncthreads();
    }
#pragma unroll
    for (int off = 32; off; off >>= 1) ssum += __shfl_xor(ssum, off, 64);
    if (lane == 0) red[wave] = ssum;
    __syncthreads();
    float inv = 1.f / (red[0] + red[1] + red[2] + red[3]);

    if (act) {
        int fb = 8 * tid;
        unsigned short o[8];
#pragma unroll
        for (int t = 0; t < 8; ++t) {
            int f = fb + t;
            o[t] = f2bu((f < FOUT) ? fmaxf(acc[t] * inv + b2f(bias2[f]), 0.f) : 0.f);
        }
        uint4 pk;
        pk.x = (unsigned)o[0] | ((unsigned)o[1] << 16);
        pk.y = (unsigned)o[2] | ((unsigned)o[3] << 16);
        pk.z = (unsigned)o[4] | ((unsigned)o[5] << 16);
        pk.w = (unsigned)o[6] | ((unsigned)o[7] << 16);
        *(uint4*)(h2 + (size_t)v * KP + fb) = pk;
    }
}

// ---------------- final: out = sigmoid(H @ H^T), bf16 MFMA, 1-D triangular grid ----------------
__global__ __launch_bounds__(256) void k_gemm_sig(const bf16_t* __restrict__ Hm,
                                                  float* __restrict__ out) {
    // decode linear tile id -> (by, bx) with bx >= by
    int t = blockIdx.x;
    int by = (int)((2 * NTILE + 1 - sqrtf((float)(2 * NTILE + 1) * (2 * NTILE + 1) - 8.0f * t)) * 0.5f);
    if (by < 0) by = 0;
    if (by > NTILE - 1) by = NTILE - 1;
    while (by + 1 < NTILE && (by + 1) * NTILE - ((by + 1) * by) / 2 <= t) ++by;
    while (by > 0 && by * NTILE - (by * (by - 1)) / 2 > t) --by;
    int bx = by + (t - (by * NTILE - (by * (by - 1)) / 2));

    __shared__ __align__(16) bf16_t As[128 * 32];
    __shared__ __align__(16) bf16_t Bs[128 * 32];
    const int tid = threadIdx.x;
    const int wave = tid >> 6;
    const int lane = tid & 63;
    const int rowA0 = by * 128;
    const int rowB0 = bx * 128;

    const int sRow  = wave * 16 + (lane >> 2);
    const int sSlot = (lane & 3) ^ ((lane >> 2) & 3);
    const bf16_t* gA = Hm + (size_t)(rowA0 + sRow) * KP + sSlot * 8;
    const bf16_t* gB = Hm + (size_t)(rowB0 + sRow) * KP + sSlot * 8;

    f32x4 acc[4][4] = {};

    const int wrow = wave >> 1, wcol = wave & 1;
    const int r = lane & 15, q = lane >> 4;
    const int rslot = q ^ (r & 3);
    const __bf16* Asb = (const __bf16*)As;
    const __bf16* Bsb = (const __bf16*)Bs;

    for (int kt = 0; kt < KP / 32; ++kt) {
        const int k0 = kt * 32;
#pragma unroll
        for (int c = 0; c < 2; ++c) {
            __builtin_amdgcn_global_load_lds(
                (const __attribute__((address_space(1))) void*)(gA + (size_t)c * 64 * KP + k0),
                (__attribute__((address_space(3))) void*)((char*)As + c * 4096 + wave * 1024),
                16, 0, 0);
            __builtin_amdgcn_global_load_lds(
                (const __attribute__((address_space(1))) void*)(gB + (size_t)c * 64 * KP + k0),
                (__attribute__((address_space(3))) void*)((char*)Bs + c * 4096 + wave * 1024),
                16, 0, 0);
        }
        __syncthreads();
        bf16x8 af[4], bfr[4];
#pragma unroll
        for (int mi = 0; mi < 4; ++mi)
            af[mi] = *(const bf16x8*)(Asb + ((wrow * 64 + mi * 16 + r) * 32 + rslot * 8));
#pragma unroll
        for (int ni = 0; ni < 4; ++ni)
            bfr[ni] = *(const bf16x8*)(Bsb + ((wcol * 64 + ni * 16 + r) * 32 + rslot * 8));
#pragma unroll
        for (int mi = 0; mi < 4; ++mi)
#pragma unroll
            for (int ni = 0; ni < 4; ++ni)
                acc[mi][ni] = __builtin_amdgcn_mfma_f32_16x16x32_bf16(af[mi], bfr[ni], acc[mi][ni], 0, 0, 0);
        __syncthreads();
    }

    // epilogue. C/D layout: col=lane&15, row=(lane>>4)*4+reg. N%4==0, row0%4==0.
#pragma unroll
    for (int mi = 0; mi < 4; ++mi) {
        const int row0 = rowA0 + wrow * 64 + mi * 16 + q * 4;
#pragma unroll
        for (int ni = 0; ni < 4; ++ni) {
            const int col = rowB0 + wcol * 64 + ni * 16 + r;
            if (col < NNODES && row0 < NNODES) {
                f32x4 s;
#pragma unroll
                for (int r2 = 0; r2 < 4; ++r2)
                    s[r2] = 1.f / (1.f + __expf(-acc[mi][ni][r2]));
#pragma unroll
                for (int r2 = 0; r2 < 4; ++r2)
                    out[(size_t)(row0 + r2) * NNODES + col] = s[r2];
                if (bx != by)   // mirrored tile: contiguous float4 store
                    *(f32x4*)(out + (size_t)col * NNODES + row0) = s;
            }
        }
    }
}

extern "C" void kernel_launch(void* const* d_in, const int* in_sizes, int n_in,
                              void* d_out, int out_size, void* d_ws, size_t ws_size,
                              hipStream_t stream) {
    const bf16_t* x   = (const bf16_t*)d_in[0];
    const int*    ei  = (const int*)d_in[1];
    const bf16_t* W1  = (const bf16_t*)d_in[2];
    const bf16_t* as1 = (const bf16_t*)d_in[3];
    const bf16_t* ad1 = (const bf16_t*)d_in[4];
    const bf16_t* b1  = (const bf16_t*)d_in[5];
    const bf16_t* W2  = (const bf16_t*)d_in[6];
    const bf16_t* as2 = (const bf16_t*)d_in[7];
    const bf16_t* ad2 = (const bf16_t*)d_in[8];
    const bf16_t* b2  = (const bf16_t*)d_in[9];
    float* out = (float*)d_out;   // output 0 f32 [N][N], output 1 f32 [2][E]

    // Scratch lives inside d_out's adjacency region (576 MB f32), dead until
    // k_gemm_sig overwrites it. Only h2 (read during final GEMM) is in d_ws.
    char* obuf = (char*)d_out;
    size_t off = 0;
    auto carve = [&](size_t bytes) {
        char* p = obuf + off;
        off += (bytes + 255) & ~(size_t)255;
        return p;
    };
    float* h1pre  = (float*)carve((size_t)NNODES * FHID * 4);
    float* al1    = (float*)carve((size_t)NNODES * 4);
    float* ar1    = (float*)carve((size_t)NNODES * 4);
    float* h1     = (float*)carve((size_t)NNODES * FHID * 4);
    float* al2    = (float*)carve((size_t)NNODES * 4);
    float* ar2    = (float*)carve((size_t)NNODES * 4);
    int*   deg    = (int*)carve((size_t)NNODES * 4);
    int*   rowptr = (int*)carve((size_t)(NNODES + 1) * 4);
    int*   cursor = (int*)carve((size_t)NNODES * 4);
    int*   csrc   = (int*)carve((size_t)NETOT * 4);
    unsigned char* h2pre = (unsigned char*)carve((size_t)NNODES * KP);  // fp8
    bf16_t* h2 = (bf16_t*)d_ws;   // [MP][KP] bf16 = 34.65 MB
    (void)ws_size; (void)in_sizes; (void)n_in; (void)out_size;

    hipLaunchKernelGGL(k_init,    dim3(256), dim3(256), 0, stream, deg, h2);
    hipLaunchKernelGGL(k_count,   dim3((NEDGES + 255) / 256), dim3(256), 0, stream, ei, deg);
    hipLaunchKernelGGL(k_scan,    dim3(1), dim3(1024), 0, stream, deg, rowptr, cursor);
    hipLaunchKernelGGL(k_fill,    dim3((2 * NEDGES + 255) / 256), dim3(256), 0, stream,
                       ei, cursor, csrc, out);
    hipLaunchKernelGGL(k_linear1, dim3((NNODES + 255) / 256), dim3(256), 0, stream,
                       x, W1, as1, ad1, h1pre, al1, ar1);
    hipLaunchKernelGGL(k_agg1,    dim3(NNODES / 4), dim3(256), 0, stream,
                       h1pre, al1, ar1, rowptr, csrc, b1, h1);
    hipLaunchKernelGGL(k_linear2, dim3(NNODES / 4), dim3(256), 0, stream,
                       h1, W2, as2, ad2, h2pre, al2, ar2);
    hipLaunchKernelGGL(k_agg2,    dim3(NNODES), dim3(256), 0, stream,
                       h2pre, al2, ar2, rowptr, csrc, b2, h2);
    hipLaunchKernelGGL(k_gemm_sig, dim3(NTRI), dim3(256), 0, stream, h2, out);
}